// Round 14
// baseline (1658.160 us; speedup 1.0000x reference)
//
#include <hip/hip_runtime.h>
#include <hip/hip_bf16.h>

#define T_ 64
#define B_ 64
#define E_ 512
#define H_ 1024
#define V_ 10000
#define TB 4096   // T_*B_
#define BH 65536  // B_*H_

typedef unsigned short u16;
typedef unsigned int u32;
typedef unsigned long long u64;
typedef __attribute__((ext_vector_type(8))) short short8v;
typedef __attribute__((ext_vector_type(4))) float f32x4;

__device__ inline f32x4 mfma_bf16(short8v a, short8v b, f32x4 c) {
  return __builtin_amdgcn_mfma_f32_16x16x32_bf16(a, b, c, 0, 0, 0);
}

__device__ inline u16 f2bf(float f) {
  unsigned u = __float_as_uint(f);
  unsigned r = (u + 0x7fffu + ((u >> 16) & 1u)) >> 16;
  return (u16)r;
}
__device__ inline float bf2f(u16 h) { return __uint_as_float(((unsigned)h) << 16); }

// ---------------- merged prep: convert weights + gather + bias + init ----------------

__global__ void k_prep(const float* __restrict__ Wr0, const float* __restrict__ Wz0,
                       const float* __restrict__ Wh0, const float* __restrict__ Ur,
                       const float* __restrict__ Uz, const float* __restrict__ Uh,
                       const float* __restrict__ WrR, const float* __restrict__ WzR,
                       const float* __restrict__ WhR, const float* __restrict__ Wout,
                       const int* __restrict__ idx, const float* __restrict__ emb,
                       const float* __restrict__ bur, const float* __restrict__ buz,
                       const float* __restrict__ buh, const float* __restrict__ brR,
                       const float* __restrict__ bzR, const float* __restrict__ bhR,
                       const float* __restrict__ hidden,
                       u16* __restrict__ W0cat, u16* __restrict__ U0cat,
                       u16* __restrict__ U1W, u16* __restrict__ Woutb,
                       u16* __restrict__ x_bf, float* __restrict__ bias0,
                       float* __restrict__ bias1, u16* __restrict__ h0P,
                       u16* __restrict__ h1P) {
  const int HE = H_ * E_;
  const int HH = H_ * H_;
  const size_t n0 = 3u * (size_t)HE;          // 1572864
  const size_t n1 = n0 + 3u * (size_t)HH;     // 4718592
  const size_t n2 = n1 + 3072u * 2048u;       // 11010048
  const size_t n3 = n2 + (size_t)V_ * H_;     // 21250048
  const size_t n4 = n3 + (size_t)TB * E_;     // 23347200
  const size_t n5 = n4 + 3072;
  const size_t n6 = n5 + 65536;
  size_t i = (size_t)blockIdx.x * 256 + threadIdx.x;
  const size_t stride = (size_t)gridDim.x * 256;
  for (; i < n6; i += stride) {
    if (i < n0) {
      int g = (int)(i >> 19), off = (int)(i & (HE - 1));
      const float* s = g == 0 ? Wr0 : (g == 1 ? Wz0 : Wh0);
      W0cat[i] = f2bf(s[off]);
    } else if (i < n1) {
      size_t j = i - n0;
      int g = (int)(j >> 20), off = (int)(j & (HH - 1));
      const float* s = g == 0 ? Ur : (g == 1 ? Uz : Uh);
      U0cat[j] = f2bf(s[off]);
    } else if (i < n2) {
      size_t k = i - n1;
      int row = (int)(k >> 11), kk = (int)(k & 2047);
      int g = row >> 10, jj = row & 1023;
      const float* su = g == 0 ? Ur : (g == 1 ? Uz : Uh);
      const float* sw = g == 0 ? WrR : (g == 1 ? WzR : WhR);
      float v = (kk < 1024) ? su[(size_t)HH + (size_t)jj * 1024 + kk]
                            : sw[(size_t)jj * 1024 + (kk - 1024)];
      U1W[k] = f2bf(v);
    } else if (i < n3) {
      size_t m = i - n2;
      Woutb[m] = f2bf(Wout[m]);
    } else if (i < n4) {
      size_t j = i - n3;
      int row = (int)(j >> 9), e = (int)(j & 511);
      x_bf[j] = f2bf(emb[(size_t)idx[row] * E_ + e]);
    } else if (i < n5) {
      int j = (int)(i - n4);
      int seg = j >> 10, col = j & 1023;
      float b0, b1;
      if (seg == 0)      { b0 = bur[col]; b1 = brR[col] + bur[H_ + col]; }
      else if (seg == 1) { b0 = buz[col]; b1 = bzR[col] + buz[H_ + col]; }
      else               { b0 = buh[col]; b1 = bhR[col] + buh[H_ + col]; }
      bias0[j] = b0; bias1[j] = b1;
    } else {
      int j = (int)(i - n5);
      int row = j >> 10, c = j & 1023;
      int dst = ((c >> 4) << 10) + (row << 4) + (c & 15);
      h0P[dst] = f2bf(hidden[j]);
      h1P[dst] = f2bf(hidden[BH + j]);
    }
  }
}

// ---------------- GEMM 1: X = x_emb @ W0cat^T + bias0, packed-X bf16 out ----------------

__global__ __launch_bounds__(256, 2) void k_gemmX(const u16* __restrict__ A,
                                                  const u16* __restrict__ Wt,
                                                  const float* __restrict__ bias,
                                                  u16* __restrict__ XP) {
  const int m0 = blockIdx.x * 128, n0 = blockIdx.y * 128;
  const int wid = threadIdx.x >> 6, lane = threadIdx.x & 63;
  const int wm = wid >> 1, wn = wid & 1;
  const int lrow = lane & 15, lk = (lane >> 4) * 8;
  f32x4 acc[4][4] = {};
  const u16* Ab = A + (size_t)(m0 + wm * 64 + lrow) * 512 + lk;
  const u16* Wb = Wt + (size_t)(n0 + wn * 64 + lrow) * 512 + lk;
  for (int ks = 0; ks < 512; ks += 32) {
    short8v a[4], b[4];
#pragma unroll
    for (int f = 0; f < 4; f++) a[f] = *(const short8v*)(Ab + (size_t)f * 16 * 512 + ks);
#pragma unroll
    for (int f = 0; f < 4; f++) b[f] = *(const short8v*)(Wb + (size_t)f * 16 * 512 + ks);
#pragma unroll
    for (int i = 0; i < 4; i++)
#pragma unroll
      for (int j = 0; j < 4; j++) acc[i][j] = mfma_bf16(a[i], b[j], acc[i][j]);
  }
  const int drow0 = (lane >> 4) * 4, dcol = lane & 15;
#pragma unroll
  for (int i = 0; i < 4; i++)
#pragma unroll
    for (int j = 0; j < 4; j++) {
      int col = n0 + wn * 64 + j * 16 + dcol;
      float bv = bias[col];
      int g = col >> 10, cg = (col & 1023) >> 4, cc = col & 15;
#pragma unroll
      for (int v = 0; v < 4; v++) {
        int row = m0 + wm * 64 + i * 16 + drow0 + v;
        int t = row >> 6, rr = row & 63;
        XP[(((size_t)t * 64 + cg) * 64 + rr) * 48 + g * 16 + cc] = f2bf(acc[i][j][v] + bv);
      }
    }
}

// ---------------- GEMM 2: logits, XCD-affine N-partitioning ----------------

__global__ __launch_bounds__(256, 2) void k_gemmL(const u16* __restrict__ AP,
                                                  const u16* __restrict__ Wt,
                                                  const float* __restrict__ bias,
                                                  float* __restrict__ C) {
  const int xcd = blockIdx.x & 7, idx = blockIdx.x >> 3;
  const int nt = xcd * 10 + (idx % 10);
  const int mt = idx / 10;
  if (nt >= 79) return;
  const int m0 = mt * 128, n0 = nt * 128;
  const int wid = threadIdx.x >> 6, lane = threadIdx.x & 63;
  const int wm = wid >> 1, wn = wid & 1;
  const int lrow = lane & 15, lk = (lane >> 4) * 8;
  const int lkb = lk >> 4, lkc = lk & 15;
  f32x4 acc[4][4] = {};
  const int rowhi = (m0 + wm * 64) >> 6;
  const u16* Ab = AP + (size_t)rowhi * BH + (size_t)lkb * 1024 + lrow * 16 + lkc;
  const u16* Wb = Wt + (size_t)(n0 + wn * 64 + lrow) * 1024 + lk;
  bool nvalid[4];
#pragma unroll
  for (int f = 0; f < 4; f++) nvalid[f] = (n0 + wn * 64 + f * 16 + lrow) < V_;
  const short8v zv = {};
  for (int ks = 0; ks < 1024; ks += 32) {
    short8v a[4], b[4];
#pragma unroll
    for (int f = 0; f < 4; f++) a[f] = *(const short8v*)(Ab + ks * 64 + f * 256);
#pragma unroll
    for (int f = 0; f < 4; f++)
      b[f] = nvalid[f] ? *(const short8v*)(Wb + (size_t)f * 16 * 1024 + ks) : zv;
#pragma unroll
    for (int i = 0; i < 4; i++)
#pragma unroll
      for (int j = 0; j < 4; j++) acc[i][j] = mfma_bf16(a[i], b[j], acc[i][j]);
  }
  const int drow0 = (lane >> 4) * 4, dcol = lane & 15;
#pragma unroll
  for (int i = 0; i < 4; i++)
#pragma unroll
    for (int j = 0; j < 4; j++) {
      int col = n0 + wn * 64 + j * 16 + dcol;
      if (col >= V_) continue;
      float bv = bias[col];
#pragma unroll
      for (int v = 0; v < 4; v++) {
        int row = m0 + wm * 64 + i * 16 + drow0 + v;
        C[(size_t)row * V_ + col] = acc[i][j][v] + bv;
      }
    }
}

// ---------------- recurrence: latency-hiding reschedule ----------------
// 128 blocks x 256 thr. gbid<64: L0; 64..127: L1. Direct slot polling (R13).
// New: R-MFMAs before the r-publish, Z-MFMAs after (earlier signal, hidden visibility);
// L1 prefetches h0[t+2] into registers before the rh1 wait (unrolled x2, no reload);
// L1's two polls run in different waves concurrently; L0 prefetches X[t+1] across its
// rh wait.

__device__ inline void pollall(const int* slots, int tgt) {
  const int lane = threadIdx.x & 63;
  const int* p = slots + lane * 32;
  for (;;) {
    int v = __hip_atomic_load(p, __ATOMIC_RELAXED, __HIP_MEMORY_SCOPE_AGENT);
    if (__all(v >= tgt)) break;
    __builtin_amdgcn_s_sleep(1);
  }
}

__global__ __launch_bounds__(256, 1) void k_recur(
    const u16* __restrict__ U0, const u16* __restrict__ U1W,
    const u16* __restrict__ XP, const float* __restrict__ bias1,
    const float* __restrict__ hidden,
    u16* __restrict__ h0P, u16* __restrict__ h1P,
    u16* __restrict__ r0P, u16* __restrict__ r1P,
    int* __restrict__ flags, float* __restrict__ hfin) {
  __shared__ __align__(16) u16 wlds[65536];  // 128 KiB

  const int tid = threadIdx.x, gbid = blockIdx.x;
  const int lay = gbid >> 6;
  const int cg = gbid & 63;
  const int jr = cg * 16;
  const int wid = tid >> 6, lane = tid & 63;
  const int lrow = lane & 15, lk = (lane >> 4) * 8;
  const int lk3 = lk >> 3, x7 = lrow & 7;
  const int drow0 = (lane >> 4) * 4, dcol = lane & 15;
  const int abase = (lk >> 4) * 1024 + (wid * 16 + lrow) * 16 + (lk & 15);
  const int KLS = lay ? 11 : 10;
  int* f0s = flags;          // 64 slots x 32 ints
  int* f1s = flags + 2048;
  int* myslot = (lay ? f1s : f0s) + cg * 32;

  {  // stage weights into LDS (swizzled 16B chunks)
    const u16* Wg = lay ? U1W : U0;
    const int lCPR = lay ? 8 : 7;
    const int NG = lay ? 2 : 3;
    const int total = NG << (4 + lCPR);
    const int KL = 1 << KLS;
    for (int idx = tid; idx < total; idx += 256) {
      int r16 = idx >> lCPR;
      int ch = idx & ((1 << lCPR) - 1);
      int g = r16 >> 4, r = r16 & 15;
      short8v v = *(const short8v*)(Wg + (size_t)((g << 10) + jr + r) * KL + (ch << 3));
      *(short8v*)&wlds[((size_t)r16 << KLS) + ((ch ^ (r & 7)) << 3)] = v;
    }
  }
  __syncthreads();

  const int lbR = lrow << KLS;
  const int lbZ = (16 + lrow) << KLS;
  const int lbH = (32 + lrow) << KLS;  // L0 only
  const u16* Whg = U1W + (size_t)(2048 + jr + lrow) * 2048 + lk;  // L1 Wh (global)
  const int orow = wid * 16 + drow0;

  float hreg[4];
#pragma unroll
  for (int v = 0; v < 4; v++)
    hreg[v] = hidden[(size_t)lay * BH + (size_t)(orow + v) * 1024 + jr + dcol];

  if (!lay) {
    // ================= layer 0 =================
    float xr[4], xz[4], xh[4];
    {
      const u16* xb = XP + (((size_t)0 * 64 + cg) * 64 + orow) * 48 + dcol;
#pragma unroll
      for (int v = 0; v < 4; v++) {
        xr[v] = bf2f(xb[v * 48]);
        xz[v] = bf2f(xb[v * 48 + 16]);
        xh[v] = bf2f(xb[v * 48 + 32]);
      }
    }
    for (int t = 0; t < T_; t++) {
      float zreg[4];
      if (t) { if (wid == 0) pollall(f0s, 2 * t); __syncthreads(); }
      // burst h0[t]
      short8v av[32];
      {
        const u16* Ab = h0P + (size_t)t * BH + abase;
#pragma unroll
        for (int i = 0; i < 32; i++) av[i] = *(const short8v*)(Ab + i * 2048);
      }
      // R gate only -> publish rh early
      f32x4 ar = {};
#pragma unroll
      for (int i = 0; i < 32; i++) {
        const int sw = (((i * 4) + lk3) ^ x7) << 3;
        ar = mfma_bf16(av[i], *(short8v*)&wlds[lbR + sw], ar);
      }
      u16* rtile = r0P + (size_t)t * BH + (size_t)cg * 1024;
#pragma unroll
      for (int v = 0; v < 4; v++) {
        float r = 1.f / (1.f + __expf(-(ar[v] + xr[v])));
        u16 me = f2bf(r * hreg[v]);
        int oth = __shfl_xor((int)me, 1);
        if (!(dcol & 1)) {
          u32 pk = (u32)me | ((u32)(u16)oth << 16);
          __hip_atomic_store((u32*)(rtile + (orow + v) * 16 + dcol), pk,
                             __ATOMIC_RELAXED, __HIP_MEMORY_SCOPE_AGENT);
        }
      }
      asm volatile("s_waitcnt vmcnt(0)" ::: "memory");
      __syncthreads();
      if (tid == 0)
        __hip_atomic_store(myslot, 2 * t + 1, __ATOMIC_RELAXED, __HIP_MEMORY_SCOPE_AGENT);
      // Z gate (reuses av) — hides signal visibility
      f32x4 az = {};
#pragma unroll
      for (int i = 0; i < 32; i++) {
        const int sw = (((i * 4) + lk3) ^ x7) << 3;
        az = mfma_bf16(av[i], *(short8v*)&wlds[lbZ + sw], az);
      }
#pragma unroll
      for (int v = 0; v < 4; v++) zreg[v] = 1.f / (1.f + __expf(-(az[v] + xz[v])));
      // prefetch X[t+1] — hides rh wait
      float nxr[4], nxz[4], nxh[4];
      {
        int tn = t + 1 < T_ ? t + 1 : T_ - 1;
        const u16* xb = XP + (((size_t)tn * 64 + cg) * 64 + orow) * 48 + dcol;
#pragma unroll
        for (int v = 0; v < 4; v++) {
          nxr[v] = bf2f(xb[v * 48]);
          nxz[v] = bf2f(xb[v * 48 + 16]);
          nxh[v] = bf2f(xb[v * 48 + 32]);
        }
      }
      // wait rh0[t]
      if (wid == 0) pollall(f0s, 2 * t + 1);
      __syncthreads();
      // stage B
      f32x4 ah = {};
      {
        const u16* Abr = r0P + (size_t)t * BH + abase;
        short8v avr[32];
#pragma unroll
        for (int i = 0; i < 32; i++) avr[i] = *(const short8v*)(Abr + i * 2048);
#pragma unroll
        for (int i = 0; i < 32; i++) {
          const int sw = (((i * 4) + lk3) ^ x7) << 3;
          ah = mfma_bf16(avr[i], *(short8v*)&wlds[lbH + sw], ah);
        }
      }
      u16* htile = h0P + (size_t)(t + 1) * BH + (size_t)cg * 1024;
#pragma unroll
      for (int v = 0; v < 4; v++) {
        float th = tanhf(ah[v] + xh[v]);
        float hn = (1.f - zreg[v]) * hreg[v] + zreg[v] * th;
        hreg[v] = hn;
        u16 me = f2bf(hn);
        int oth = __shfl_xor((int)me, 1);
        if (!(dcol & 1)) {
          u32 pk = (u32)me | ((u32)(u16)oth << 16);
          __hip_atomic_store((u32*)(htile + (orow + v) * 16 + dcol), pk,
                             __ATOMIC_RELAXED, __HIP_MEMORY_SCOPE_AGENT);
        }
        if (t == T_ - 1)
          hfin[(size_t)(orow + v) * 1024 + jr + dcol] = hn;
      }
      asm volatile("s_waitcnt vmcnt(0)" ::: "memory");
      __syncthreads();
      if (tid == 0)
        __hip_atomic_store(myslot, 2 * t + 2, __ATOMIC_RELAXED, __HIP_MEMORY_SCOPE_AGENT);
#pragma unroll
      for (int v = 0; v < 4; v++) { xr[v] = nxr[v]; xz[v] = nxz[v]; xh[v] = nxh[v]; }
    }
  } else {
    // ================= layer 1 =================
    float bR = bias1[jr + dcol];
    float bZ = bias1[1024 + jr + dcol];
    float bH = bias1[2048 + jr + dcol];
    if (wid == 0) pollall(f0s, 2);  // h0[1] ready
    __syncthreads();
    short8v avA[32], avB[32];
    {
      const u16* Ab = h0P + (size_t)1 * BH + abase;
#pragma unroll
      for (int i = 0; i < 32; i++) avA[i] = *(const short8v*)(Ab + i * 2048);
    }

    auto body = [&](int t, short8v (&avIn)[32], short8v (&avOut)[32]) {
      float zreg[4];
      // ---- A1: R+Z over h0[t+1] (registers; runs right after prev signal) ----
      f32x4 ar = {}, az = {};
#pragma unroll
      for (int i = 0; i < 32; i++) {
        const int sw = ((128 + i * 4 + lk3) ^ x7) << 3;
        ar = mfma_bf16(avIn[i], *(short8v*)&wlds[lbR + sw], ar);
        az = mfma_bf16(avIn[i], *(short8v*)&wlds[lbZ + sw], az);
      }
      // ---- parallel waits: wave0 -> h1[t]; wave1 -> L0 two steps ahead ----
      if (wid == 0) {
        if (t) pollall(f1s, 2 * t);
      } else if (wid == 1) {
        int tgt = 2 * (t + 2);
        pollall(f0s, tgt > 2 * T_ ? 2 * T_ : tgt);
      }
      __syncthreads();
      // ---- A2: burst h1[t]; R first -> publish rh early ----
      short8v av1[32];
      {
        const u16* Ab1 = h1P + (size_t)t * BH + abase;
#pragma unroll
        for (int i = 0; i < 32; i++) av1[i] = *(const short8v*)(Ab1 + i * 2048);
      }
#pragma unroll
      for (int i = 0; i < 32; i++) {
        const int sw = ((i * 4 + lk3) ^ x7) << 3;
        ar = mfma_bf16(av1[i], *(short8v*)&wlds[lbR + sw], ar);
      }
      u16* rtile = r1P + (size_t)t * BH + (size_t)cg * 1024;
#pragma unroll
      for (int v = 0; v < 4; v++) {
        float r = 1.f / (1.f + __expf(-(ar[v] + bR)));
        u16 me = f2bf(r * hreg[v]);
        int oth = __shfl_xor((int)me, 1);
        if (!(dcol & 1)) {
          u32 pk = (u32)me | ((u32)(u16)oth << 16);
          __hip_atomic_store((u32*)(rtile + (orow + v) * 16 + dcol), pk,
                             __ATOMIC_RELAXED, __HIP_MEMORY_SCOPE_AGENT);
        }
      }
      asm volatile("s_waitcnt vmcnt(0)" ::: "memory");
      __syncthreads();
      if (tid == 0)
        __hip_atomic_store(myslot, 2 * t + 1, __ATOMIC_RELAXED, __HIP_MEMORY_SCOPE_AGENT);
      // ---- Z over h1[t] (av1 reuse) — hides signal visibility ----
#pragma unroll
      for (int i = 0; i < 32; i++) {
        const int sw = ((i * 4 + lk3) ^ x7) << 3;
        az = mfma_bf16(av1[i], *(short8v*)&wlds[lbZ + sw], az);
      }
#pragma unroll
      for (int v = 0; v < 4; v++) zreg[v] = 1.f / (1.f + __expf(-(az[v] + bZ)));
      // ---- B1: h0[t+1] x Wh (avIn reuse, Whg L2 stream) — hides wait ----
      f32x4 ah = {};
#pragma unroll
      for (int i = 0; i < 32; i++)
        ah = mfma_bf16(avIn[i], *(const short8v*)(Whg + 1024 + i * 32), ah);
      // ---- prefetch h0[t+2] for next step (in flight across the wait) ----
      {
        int ts = t + 2 < 64 ? t + 2 : 64;
        const u16* An = h0P + (size_t)ts * BH + abase;
#pragma unroll
        for (int i = 0; i < 32; i++) avOut[i] = *(const short8v*)(An + i * 2048);
      }
      // ---- wait rh1[t] ----
      if (wid == 0) pollall(f1s, 2 * t + 1);
      __syncthreads();
      // ---- B2: burst rh1[t] x Wh ----
      {
        const u16* Abr = r1P + (size_t)t * BH + abase;
        short8v avr[32];
#pragma unroll
        for (int i = 0; i < 32; i++) avr[i] = *(const short8v*)(Abr + i * 2048);
#pragma unroll
        for (int i = 0; i < 32; i++)
          ah = mfma_bf16(avr[i], *(const short8v*)(Whg + i * 32), ah);
      }
      u16* htile = h1P + (size_t)(t + 1) * BH + (size_t)cg * 1024;
#pragma unroll
      for (int v = 0; v < 4; v++) {
        float th = tanhf(ah[v] + bH);
        float hn = (1.f - zreg[v]) * hreg[v] + zreg[v] * th;
        hreg[v] = hn;
        u16 me = f2bf(hn);
        int oth = __shfl_xor((int)me, 1);
        if (!(dcol & 1)) {
          u32 pk = (u32)me | ((u32)(u16)oth << 16);
          __hip_atomic_store((u32*)(htile + (orow + v) * 16 + dcol), pk,
                             __ATOMIC_RELAXED, __HIP_MEMORY_SCOPE_AGENT);
        }
        if (t == T_ - 1)
          hfin[(size_t)BH + (size_t)(orow + v) * 1024 + jr + dcol] = hn;
      }
      asm volatile("s_waitcnt vmcnt(0)" ::: "memory");
      __syncthreads();
      if (tid == 0)
        __hip_atomic_store(myslot, 2 * t + 2, __ATOMIC_RELAXED, __HIP_MEMORY_SCOPE_AGENT);
    };

    for (int t = 0; t < T_; t += 2) {
      body(t, avA, avB);
      body(t + 1, avB, avA);
    }
  }
}

// ---------------- launcher ----------------

extern "C" void kernel_launch(void* const* d_in, const int* in_sizes, int n_in,
                              void* d_out, int out_size, void* d_ws, size_t ws_size,
                              hipStream_t stream) {
  const int* inputs = (const int*)d_in[0];
  const float* hidden = (const float*)d_in[1];
  const float* emb = (const float*)d_in[2];
  const float* Wr0 = (const float*)d_in[3];
  const float* Wz0 = (const float*)d_in[4];
  const float* Wh0 = (const float*)d_in[5];
  const float* WrR = (const float*)d_in[6];
  const float* WzR = (const float*)d_in[7];
  const float* WhR = (const float*)d_in[8];
  const float* brR = (const float*)d_in[9];
  const float* bzR = (const float*)d_in[10];
  const float* bhR = (const float*)d_in[11];
  const float* Ur = (const float*)d_in[12];
  const float* Uz = (const float*)d_in[13];
  const float* Uh = (const float*)d_in[14];
  const float* bur = (const float*)d_in[15];
  const float* buz = (const float*)d_in[16];
  const float* buh = (const float*)d_in[17];
  const float* Wout = (const float*)d_in[18];
  const float* bout = (const float*)d_in[19];
  float* out = (float*)d_out;

  char* ws = (char*)d_ws;
  size_t off = 0;
  auto alloc = [&](size_t bytes) -> void* {
    void* p = ws + off;
    off += (bytes + 255) & ~(size_t)255;
    return p;
  };
  u16* x_bf  = (u16*)alloc((size_t)TB * E_ * 2);
  u16* W0cat = (u16*)alloc((size_t)3072 * 512 * 2);
  u16* U0cat = (u16*)alloc((size_t)3072 * 1024 * 2);
  u16* U1W   = (u16*)alloc((size_t)3072 * 2048 * 2);
  u16* Woutb = (u16*)alloc((size_t)V_ * H_ * 2);
  float* bias0 = (float*)alloc(3072 * 4);
  float* bias1 = (float*)alloc(3072 * 4);
  u16* XP    = (u16*)alloc((size_t)TB * 3072 * 2);
  u16* h0P   = (u16*)alloc((size_t)(T_ + 1) * BH * 2);
  u16* h1P   = (u16*)alloc((size_t)(T_ + 1) * BH * 2);
  u16* r0P   = (u16*)alloc((size_t)T_ * BH * 2);
  u16* r1P   = (u16*)alloc((size_t)T_ * BH * 2);
  int* flags = (int*)alloc(32768);
  (void)ws_size; (void)in_sizes; (void)n_in; (void)out_size;

  hipMemsetAsync(flags, 0, 32768, stream);

  k_prep<<<2048, 256, 0, stream>>>(Wr0, Wz0, Wh0, Ur, Uz, Uh, WrR, WzR, WhR, Wout,
                                   inputs, emb, bur, buz, buh, brR, bzR, bhR, hidden,
                                   W0cat, U0cat, U1W, Woutb, x_bf, bias0, bias1,
                                   h0P, h1P);
  k_gemmX<<<dim3(32, 24), 256, 0, stream>>>(x_bf, W0cat, bias0, XP);
  k_recur<<<128, 256, 0, stream>>>(U0cat, U1W, XP, bias1, hidden, h0P, h1P,
                                   r0P, r1P, flags, out + (size_t)TB * V_);
  k_gemmL<<<2560, 256, 0, stream>>>(h1P + BH, Woutb, bout, out);
}

// Round 15
// 1381.971 us; speedup vs baseline: 1.1999x; 1.1999x over previous
//
#include <hip/hip_runtime.h>
#include <hip/hip_bf16.h>

#define T_ 64
#define B_ 64
#define E_ 512
#define H_ 1024
#define V_ 10000
#define TB 4096   // T_*B_
#define BH 65536  // B_*H_

typedef unsigned short u16;
typedef unsigned int u32;
typedef unsigned long long u64;
typedef __attribute__((ext_vector_type(8))) short short8v;
typedef __attribute__((ext_vector_type(4))) float f32x4;

__device__ inline f32x4 mfma_bf16(short8v a, short8v b, f32x4 c) {
  return __builtin_amdgcn_mfma_f32_16x16x32_bf16(a, b, c, 0, 0, 0);
}

__device__ inline u16 f2bf(float f) {
  unsigned u = __float_as_uint(f);
  unsigned r = (u + 0x7fffu + ((u >> 16) & 1u)) >> 16;
  return (u16)r;
}
__device__ inline float bf2f(u16 h) { return __uint_as_float(((unsigned)h) << 16); }

// ---------------- merged prep ----------------

__global__ void k_prep(const float* __restrict__ Wr0, const float* __restrict__ Wz0,
                       const float* __restrict__ Wh0, const float* __restrict__ Ur,
                       const float* __restrict__ Uz, const float* __restrict__ Uh,
                       const float* __restrict__ WrR, const float* __restrict__ WzR,
                       const float* __restrict__ WhR, const float* __restrict__ Wout,
                       const int* __restrict__ idx, const float* __restrict__ emb,
                       const float* __restrict__ bur, const float* __restrict__ buz,
                       const float* __restrict__ buh, const float* __restrict__ brR,
                       const float* __restrict__ bzR, const float* __restrict__ bhR,
                       const float* __restrict__ hidden,
                       u16* __restrict__ W0cat, u16* __restrict__ U0cat,
                       u16* __restrict__ U1W, u16* __restrict__ Woutb,
                       u16* __restrict__ x_bf, float* __restrict__ bias0,
                       float* __restrict__ bias1, u16* __restrict__ h0P,
                       u16* __restrict__ h1P) {
  const int HE = H_ * E_;
  const int HH = H_ * H_;
  const size_t n0 = 3u * (size_t)HE;
  const size_t n1 = n0 + 3u * (size_t)HH;
  const size_t n2 = n1 + 3072u * 2048u;
  const size_t n3 = n2 + (size_t)V_ * H_;
  const size_t n4 = n3 + (size_t)TB * E_;
  const size_t n5 = n4 + 3072;
  const size_t n6 = n5 + 65536;
  size_t i = (size_t)blockIdx.x * 256 + threadIdx.x;
  const size_t stride = (size_t)gridDim.x * 256;
  for (; i < n6; i += stride) {
    if (i < n0) {
      int g = (int)(i >> 19), off = (int)(i & (HE - 1));
      const float* s = g == 0 ? Wr0 : (g == 1 ? Wz0 : Wh0);
      W0cat[i] = f2bf(s[off]);
    } else if (i < n1) {
      size_t j = i - n0;
      int g = (int)(j >> 20), off = (int)(j & (HH - 1));
      const float* s = g == 0 ? Ur : (g == 1 ? Uz : Uh);
      U0cat[j] = f2bf(s[off]);
    } else if (i < n2) {
      size_t k = i - n1;
      int row = (int)(k >> 11), kk = (int)(k & 2047);
      int g = row >> 10, jj = row & 1023;
      const float* su = g == 0 ? Ur : (g == 1 ? Uz : Uh);
      const float* sw = g == 0 ? WrR : (g == 1 ? WzR : WhR);
      float v = (kk < 1024) ? su[(size_t)HH + (size_t)jj * 1024 + kk]
                            : sw[(size_t)jj * 1024 + (kk - 1024)];
      U1W[k] = f2bf(v);
    } else if (i < n3) {
      size_t m = i - n2;
      Woutb[m] = f2bf(Wout[m]);
    } else if (i < n4) {
      size_t j = i - n3;
      int row = (int)(j >> 9), e = (int)(j & 511);
      x_bf[j] = f2bf(emb[(size_t)idx[row] * E_ + e]);
    } else if (i < n5) {
      int j = (int)(i - n4);
      int seg = j >> 10, col = j & 1023;
      float b0, b1;
      if (seg == 0)      { b0 = bur[col]; b1 = brR[col] + bur[H_ + col]; }
      else if (seg == 1) { b0 = buz[col]; b1 = bzR[col] + buz[H_ + col]; }
      else               { b0 = buh[col]; b1 = bhR[col] + buh[H_ + col]; }
      bias0[j] = b0; bias1[j] = b1;
    } else {
      int j = (int)(i - n5);
      int row = j >> 10, c = j & 1023;
      int dst = ((c >> 4) << 10) + (row << 4) + (c & 15);
      h0P[dst] = f2bf(hidden[j]);
      h1P[dst] = f2bf(hidden[BH + j]);
    }
  }
}

// ---------------- GEMM 1: X = x_emb @ W0cat^T + bias0, packed-X bf16 out ----------------

__global__ __launch_bounds__(256, 2) void k_gemmX(const u16* __restrict__ A,
                                                  const u16* __restrict__ Wt,
                                                  const float* __restrict__ bias,
                                                  u16* __restrict__ XP) {
  const int m0 = blockIdx.x * 128, n0 = blockIdx.y * 128;
  const int wid = threadIdx.x >> 6, lane = threadIdx.x & 63;
  const int wm = wid >> 1, wn = wid & 1;
  const int lrow = lane & 15, lk = (lane >> 4) * 8;
  f32x4 acc[4][4] = {};
  const u16* Ab = A + (size_t)(m0 + wm * 64 + lrow) * 512 + lk;
  const u16* Wb = Wt + (size_t)(n0 + wn * 64 + lrow) * 512 + lk;
  for (int ks = 0; ks < 512; ks += 32) {
    short8v a[4], b[4];
#pragma unroll
    for (int f = 0; f < 4; f++) a[f] = *(const short8v*)(Ab + (size_t)f * 16 * 512 + ks);
#pragma unroll
    for (int f = 0; f < 4; f++) b[f] = *(const short8v*)(Wb + (size_t)f * 16 * 512 + ks);
#pragma unroll
    for (int i = 0; i < 4; i++)
#pragma unroll
      for (int j = 0; j < 4; j++) acc[i][j] = mfma_bf16(a[i], b[j], acc[i][j]);
  }
  const int drow0 = (lane >> 4) * 4, dcol = lane & 15;
#pragma unroll
  for (int i = 0; i < 4; i++)
#pragma unroll
    for (int j = 0; j < 4; j++) {
      int col = n0 + wn * 64 + j * 16 + dcol;
      float bv = bias[col];
      int g = col >> 10, cg = (col & 1023) >> 4, cc = col & 15;
#pragma unroll
      for (int v = 0; v < 4; v++) {
        int row = m0 + wm * 64 + i * 16 + drow0 + v;
        int t = row >> 6, rr = row & 63;
        XP[(((size_t)t * 64 + cg) * 64 + rr) * 48 + g * 16 + cc] = f2bf(acc[i][j][v] + bv);
      }
    }
}

// ---------------- GEMM 2: logits, XCD-affine N-partitioning ----------------

__global__ __launch_bounds__(256, 2) void k_gemmL(const u16* __restrict__ AP,
                                                  const u16* __restrict__ Wt,
                                                  const float* __restrict__ bias,
                                                  float* __restrict__ C) {
  const int xcd = blockIdx.x & 7, idx = blockIdx.x >> 3;
  const int nt = xcd * 10 + (idx % 10);
  const int mt = idx / 10;
  if (nt >= 79) return;
  const int m0 = mt * 128, n0 = nt * 128;
  const int wid = threadIdx.x >> 6, lane = threadIdx.x & 63;
  const int wm = wid >> 1, wn = wid & 1;
  const int lrow = lane & 15, lk = (lane >> 4) * 8;
  const int lkb = lk >> 4, lkc = lk & 15;
  f32x4 acc[4][4] = {};
  const int rowhi = (m0 + wm * 64) >> 6;
  const u16* Ab = AP + (size_t)rowhi * BH + (size_t)lkb * 1024 + lrow * 16 + lkc;
  const u16* Wb = Wt + (size_t)(n0 + wn * 64 + lrow) * 1024 + lk;
  bool nvalid[4];
#pragma unroll
  for (int f = 0; f < 4; f++) nvalid[f] = (n0 + wn * 64 + f * 16 + lrow) < V_;
  const short8v zv = {};
  for (int ks = 0; ks < 1024; ks += 32) {
    short8v a[4], b[4];
#pragma unroll
    for (int f = 0; f < 4; f++) a[f] = *(const short8v*)(Ab + ks * 64 + f * 256);
#pragma unroll
    for (int f = 0; f < 4; f++)
      b[f] = nvalid[f] ? *(const short8v*)(Wb + (size_t)f * 16 * 1024 + ks) : zv;
#pragma unroll
    for (int i = 0; i < 4; i++)
#pragma unroll
      for (int j = 0; j < 4; j++) acc[i][j] = mfma_bf16(a[i], b[j], acc[i][j]);
  }
  const int drow0 = (lane >> 4) * 4, dcol = lane & 15;
#pragma unroll
  for (int i = 0; i < 4; i++)
#pragma unroll
    for (int j = 0; j < 4; j++) {
      int col = n0 + wn * 64 + j * 16 + dcol;
      if (col >= V_) continue;
      float bv = bias[col];
#pragma unroll
      for (int v = 0; v < 4; v++) {
        int row = m0 + wm * 64 + i * 16 + drow0 + v;
        C[(size_t)row * V_ + col] = acc[i][j][v] + bv;
      }
    }
}

// ---------------- recurrence: R13 + register-cheap reschedule ----------------
// 128 blocks x 256 thr. gbid<64: L0; 64..127: L1. Direct slot polling.
// R-gate MFMAs -> publish rh early; Z-gate MFMAs after (reuse live av, zero extra regs).
// L1: av0 (h0 burst) reused in B1 (as R13); parallel waits in different waves.
// L0: X[t+1] prefetched across the rh wait (12 regs). NO deep double-buffer (R14 spill).

__device__ inline void pollall(const int* slots, int tgt) {
  const int lane = threadIdx.x & 63;
  const int* p = slots + lane * 32;
  for (;;) {
    int v = __hip_atomic_load(p, __ATOMIC_RELAXED, __HIP_MEMORY_SCOPE_AGENT);
    if (__all(v >= tgt)) break;
    __builtin_amdgcn_s_sleep(1);
  }
}

__global__ __launch_bounds__(256, 1) void k_recur(
    const u16* __restrict__ U0, const u16* __restrict__ U1W,
    const u16* __restrict__ XP, const float* __restrict__ bias1,
    const float* __restrict__ hidden,
    u16* __restrict__ h0P, u16* __restrict__ h1P,
    u16* __restrict__ r0P, u16* __restrict__ r1P,
    int* __restrict__ flags, float* __restrict__ hfin) {
  __shared__ __align__(16) u16 wlds[65536];  // 128 KiB

  const int tid = threadIdx.x, gbid = blockIdx.x;
  const int lay = gbid >> 6;
  const int cg = gbid & 63;
  const int jr = cg * 16;
  const int wid = tid >> 6, lane = tid & 63;
  const int lrow = lane & 15, lk = (lane >> 4) * 8;
  const int lk3 = lk >> 3, x7 = lrow & 7;
  const int drow0 = (lane >> 4) * 4, dcol = lane & 15;
  const int abase = (lk >> 4) * 1024 + (wid * 16 + lrow) * 16 + (lk & 15);
  const int KLS = lay ? 11 : 10;
  int* f0s = flags;
  int* f1s = flags + 2048;
  int* myslot = (lay ? f1s : f0s) + cg * 32;

  {  // stage weights into LDS (swizzled 16B chunks)
    const u16* Wg = lay ? U1W : U0;
    const int lCPR = lay ? 8 : 7;
    const int NG = lay ? 2 : 3;
    const int total = NG << (4 + lCPR);
    const int KL = 1 << KLS;
    for (int idx = tid; idx < total; idx += 256) {
      int r16 = idx >> lCPR;
      int ch = idx & ((1 << lCPR) - 1);
      int g = r16 >> 4, r = r16 & 15;
      short8v v = *(const short8v*)(Wg + (size_t)((g << 10) + jr + r) * KL + (ch << 3));
      *(short8v*)&wlds[((size_t)r16 << KLS) + ((ch ^ (r & 7)) << 3)] = v;
    }
  }
  __syncthreads();

  const int lbR = lrow << KLS;
  const int lbZ = (16 + lrow) << KLS;
  const int lbH = (32 + lrow) << KLS;  // L0 only
  const u16* Whg = U1W + (size_t)(2048 + jr + lrow) * 2048 + lk;  // L1 Wh (global)
  const int orow = wid * 16 + drow0;

  float hreg[4];
#pragma unroll
  for (int v = 0; v < 4; v++)
    hreg[v] = hidden[(size_t)lay * BH + (size_t)(orow + v) * 1024 + jr + dcol];

  if (!lay) {
    // ================= layer 0 =================
    float xr[4], xz[4], xh[4];
    {
      const u16* xb = XP + (((size_t)0 * 64 + cg) * 64 + orow) * 48 + dcol;
#pragma unroll
      for (int v = 0; v < 4; v++) {
        xr[v] = bf2f(xb[v * 48]);
        xz[v] = bf2f(xb[v * 48 + 16]);
        xh[v] = bf2f(xb[v * 48 + 32]);
      }
    }
    for (int t = 0; t < T_; t++) {
      float zreg[4];
      if (t) { if (wid == 0) pollall(f0s, 2 * t); __syncthreads(); }
      // burst h0[t]
      short8v av[32];
      {
        const u16* Ab = h0P + (size_t)t * BH + abase;
#pragma unroll
        for (int i = 0; i < 32; i++) av[i] = *(const short8v*)(Ab + i * 2048);
      }
      // R gate only -> publish rh early
      f32x4 ar = {};
#pragma unroll
      for (int i = 0; i < 32; i++) {
        const int sw = (((i * 4) + lk3) ^ x7) << 3;
        ar = mfma_bf16(av[i], *(short8v*)&wlds[lbR + sw], ar);
      }
      u16* rtile = r0P + (size_t)t * BH + (size_t)cg * 1024;
#pragma unroll
      for (int v = 0; v < 4; v++) {
        float r = 1.f / (1.f + __expf(-(ar[v] + xr[v])));
        u16 me = f2bf(r * hreg[v]);
        int oth = __shfl_xor((int)me, 1);
        if (!(dcol & 1)) {
          u32 pk = (u32)me | ((u32)(u16)oth << 16);
          __hip_atomic_store((u32*)(rtile + (orow + v) * 16 + dcol), pk,
                             __ATOMIC_RELAXED, __HIP_MEMORY_SCOPE_AGENT);
        }
      }
      asm volatile("s_waitcnt vmcnt(0)" ::: "memory");
      __syncthreads();
      if (tid == 0)
        __hip_atomic_store(myslot, 2 * t + 1, __ATOMIC_RELAXED, __HIP_MEMORY_SCOPE_AGENT);
      // Z gate (reuses av) — hides signal visibility
      f32x4 az = {};
#pragma unroll
      for (int i = 0; i < 32; i++) {
        const int sw = (((i * 4) + lk3) ^ x7) << 3;
        az = mfma_bf16(av[i], *(short8v*)&wlds[lbZ + sw], az);
      }
#pragma unroll
      for (int v = 0; v < 4; v++) zreg[v] = 1.f / (1.f + __expf(-(az[v] + xz[v])));
      // prefetch X[t+1] — hides rh wait
      float nxr[4], nxz[4], nxh[4];
      {
        int tn = t + 1 < T_ ? t + 1 : T_ - 1;
        const u16* xb = XP + (((size_t)tn * 64 + cg) * 64 + orow) * 48 + dcol;
#pragma unroll
        for (int v = 0; v < 4; v++) {
          nxr[v] = bf2f(xb[v * 48]);
          nxz[v] = bf2f(xb[v * 48 + 16]);
          nxh[v] = bf2f(xb[v * 48 + 32]);
        }
      }
      // wait rh0[t]
      if (wid == 0) pollall(f0s, 2 * t + 1);
      __syncthreads();
      // stage B
      f32x4 ah = {};
      {
        const u16* Abr = r0P + (size_t)t * BH + abase;
        short8v avr[32];
#pragma unroll
        for (int i = 0; i < 32; i++) avr[i] = *(const short8v*)(Abr + i * 2048);
#pragma unroll
        for (int i = 0; i < 32; i++) {
          const int sw = (((i * 4) + lk3) ^ x7) << 3;
          ah = mfma_bf16(avr[i], *(short8v*)&wlds[lbH + sw], ah);
        }
      }
      u16* htile = h0P + (size_t)(t + 1) * BH + (size_t)cg * 1024;
#pragma unroll
      for (int v = 0; v < 4; v++) {
        float th = tanhf(ah[v] + xh[v]);
        float hn = (1.f - zreg[v]) * hreg[v] + zreg[v] * th;
        hreg[v] = hn;
        u16 me = f2bf(hn);
        int oth = __shfl_xor((int)me, 1);
        if (!(dcol & 1)) {
          u32 pk = (u32)me | ((u32)(u16)oth << 16);
          __hip_atomic_store((u32*)(htile + (orow + v) * 16 + dcol), pk,
                             __ATOMIC_RELAXED, __HIP_MEMORY_SCOPE_AGENT);
        }
        if (t == T_ - 1)
          hfin[(size_t)(orow + v) * 1024 + jr + dcol] = hn;
      }
      asm volatile("s_waitcnt vmcnt(0)" ::: "memory");
      __syncthreads();
      if (tid == 0)
        __hip_atomic_store(myslot, 2 * t + 2, __ATOMIC_RELAXED, __HIP_MEMORY_SCOPE_AGENT);
#pragma unroll
      for (int v = 0; v < 4; v++) { xr[v] = nxr[v]; xz[v] = nxz[v]; xh[v] = nxh[v]; }
    }
  } else {
    // ================= layer 1 =================
    float bR = bias1[jr + dcol];
    float bZ = bias1[1024 + jr + dcol];
    float bH = bias1[2048 + jr + dcol];
    if (wid == 0) pollall(f0s, 2);  // h0[1] ready before first A-part1
    __syncthreads();
    for (int t = 0; t < T_; t++) {
      float zreg[4];
      const u16* Ab0 = h0P + (size_t)(t + 1) * BH + abase;
      // ---- A part 1: h0[t+1] burst (av0 kept live for B1) ----
      f32x4 ar = {}, az = {};
      short8v av0[32];
#pragma unroll
      for (int i = 0; i < 32; i++) av0[i] = *(const short8v*)(Ab0 + i * 2048);
#pragma unroll
      for (int i = 0; i < 32; i++) {
        const int sw = ((128 + i * 4 + lk3) ^ x7) << 3;
        ar = mfma_bf16(av0[i], *(short8v*)&wlds[lbR + sw], ar);
        az = mfma_bf16(av0[i], *(short8v*)&wlds[lbZ + sw], az);
      }
      // ---- parallel waits: wave0 -> h1[t]; wave1 -> L0 two steps ahead ----
      if (wid == 0) {
        if (t) pollall(f1s, 2 * t);
      } else if (wid == 1) {
        int tgt = 2 * (t + 2);
        pollall(f0s, tgt > 2 * T_ ? 2 * T_ : tgt);
      }
      __syncthreads();
      // ---- A part 2: burst h1[t]; R first -> publish rh early ----
      short8v av1[32];
      {
        const u16* Ab1 = h1P + (size_t)t * BH + abase;
#pragma unroll
        for (int i = 0; i < 32; i++) av1[i] = *(const short8v*)(Ab1 + i * 2048);
      }
#pragma unroll
      for (int i = 0; i < 32; i++) {
        const int sw = ((i * 4 + lk3) ^ x7) << 3;
        ar = mfma_bf16(av1[i], *(short8v*)&wlds[lbR + sw], ar);
      }
      u16* rtile = r1P + (size_t)t * BH + (size_t)cg * 1024;
#pragma unroll
      for (int v = 0; v < 4; v++) {
        float r = 1.f / (1.f + __expf(-(ar[v] + bR)));
        u16 me = f2bf(r * hreg[v]);
        int oth = __shfl_xor((int)me, 1);
        if (!(dcol & 1)) {
          u32 pk = (u32)me | ((u32)(u16)oth << 16);
          __hip_atomic_store((u32*)(rtile + (orow + v) * 16 + dcol), pk,
                             __ATOMIC_RELAXED, __HIP_MEMORY_SCOPE_AGENT);
        }
      }
      asm volatile("s_waitcnt vmcnt(0)" ::: "memory");
      __syncthreads();
      if (tid == 0)
        __hip_atomic_store(myslot, 2 * t + 1, __ATOMIC_RELAXED, __HIP_MEMORY_SCOPE_AGENT);
      // ---- Z over h1[t] (av1 reuse) — hides signal visibility ----
#pragma unroll
      for (int i = 0; i < 32; i++) {
        const int sw = ((i * 4 + lk3) ^ x7) << 3;
        az = mfma_bf16(av1[i], *(short8v*)&wlds[lbZ + sw], az);
      }
#pragma unroll
      for (int v = 0; v < 4; v++) zreg[v] = 1.f / (1.f + __expf(-(az[v] + bZ)));
      // ---- B part 1: h0[t+1] x Wh (av0 reuse, Whg L2 stream) — hides rh wait ----
      f32x4 ah = {};
#pragma unroll
      for (int i = 0; i < 32; i++)
        ah = mfma_bf16(av0[i], *(const short8v*)(Whg + 1024 + i * 32), ah);
      // ---- wait rh1[t] ----
      if (wid == 0) pollall(f1s, 2 * t + 1);
      __syncthreads();
      // ---- B part 2: burst rh1[t] x Wh ----
      {
        const u16* Abr = r1P + (size_t)t * BH + abase;
        short8v avr[32];
#pragma unroll
        for (int i = 0; i < 32; i++) avr[i] = *(const short8v*)(Abr + i * 2048);
#pragma unroll
        for (int i = 0; i < 32; i++)
          ah = mfma_bf16(avr[i], *(const short8v*)(Whg + i * 32), ah);
      }
      u16* htile = h1P + (size_t)(t + 1) * BH + (size_t)cg * 1024;
#pragma unroll
      for (int v = 0; v < 4; v++) {
        float th = tanhf(ah[v] + bH);
        float hn = (1.f - zreg[v]) * hreg[v] + zreg[v] * th;
        hreg[v] = hn;
        u16 me = f2bf(hn);
        int oth = __shfl_xor((int)me, 1);
        if (!(dcol & 1)) {
          u32 pk = (u32)me | ((u32)(u16)oth << 16);
          __hip_atomic_store((u32*)(htile + (orow + v) * 16 + dcol), pk,
                             __ATOMIC_RELAXED, __HIP_MEMORY_SCOPE_AGENT);
        }
        if (t == T_ - 1)
          hfin[(size_t)BH + (size_t)(orow + v) * 1024 + jr + dcol] = hn;
      }
      asm volatile("s_waitcnt vmcnt(0)" ::: "memory");
      __syncthreads();
      if (tid == 0)
        __hip_atomic_store(myslot, 2 * t + 2, __ATOMIC_RELAXED, __HIP_MEMORY_SCOPE_AGENT);
    }
  }
}

// ---------------- launcher ----------------

extern "C" void kernel_launch(void* const* d_in, const int* in_sizes, int n_in,
                              void* d_out, int out_size, void* d_ws, size_t ws_size,
                              hipStream_t stream) {
  const int* inputs = (const int*)d_in[0];
  const float* hidden = (const float*)d_in[1];
  const float* emb = (const float*)d_in[2];
  const float* Wr0 = (const float*)d_in[3];
  const float* Wz0 = (const float*)d_in[4];
  const float* Wh0 = (const float*)d_in[5];
  const float* WrR = (const float*)d_in[6];
  const float* WzR = (const float*)d_in[7];
  const float* WhR = (const float*)d_in[8];
  const float* brR = (const float*)d_in[9];
  const float* bzR = (const float*)d_in[10];
  const float* bhR = (const float*)d_in[11];
  const float* Ur = (const float*)d_in[12];
  const float* Uz = (const float*)d_in[13];
  const float* Uh = (const float*)d_in[14];
  const float* bur = (const float*)d_in[15];
  const float* buz = (const float*)d_in[16];
  const float* buh = (const float*)d_in[17];
  const float* Wout = (const float*)d_in[18];
  const float* bout = (const float*)d_in[19];
  float* out = (float*)d_out;

  char* ws = (char*)d_ws;
  size_t off = 0;
  auto alloc = [&](size_t bytes) -> void* {
    void* p = ws + off;
    off += (bytes + 255) & ~(size_t)255;
    return p;
  };
  u16* x_bf  = (u16*)alloc((size_t)TB * E_ * 2);
  u16* W0cat = (u16*)alloc((size_t)3072 * 512 * 2);
  u16* U0cat = (u16*)alloc((size_t)3072 * 1024 * 2);
  u16* U1W   = (u16*)alloc((size_t)3072 * 2048 * 2);
  u16* Woutb = (u16*)alloc((size_t)V_ * H_ * 2);
  float* bias0 = (float*)alloc(3072 * 4);
  float* bias1 = (float*)alloc(3072 * 4);
  u16* XP    = (u16*)alloc((size_t)TB * 3072 * 2);
  u16* h0P   = (u16*)alloc((size_t)(T_ + 1) * BH * 2);
  u16* h1P   = (u16*)alloc((size_t)(T_ + 1) * BH * 2);
  u16* r0P   = (u16*)alloc((size_t)T_ * BH * 2);
  u16* r1P   = (u16*)alloc((size_t)T_ * BH * 2);
  int* flags = (int*)alloc(32768);
  (void)ws_size; (void)in_sizes; (void)n_in; (void)out_size;

  hipMemsetAsync(flags, 0, 32768, stream);

  k_prep<<<2048, 256, 0, stream>>>(Wr0, Wz0, Wh0, Ur, Uz, Uh, WrR, WzR, WhR, Wout,
                                   inputs, emb, bur, buz, buh, brR, bzR, bhR, hidden,
                                   W0cat, U0cat, U1W, Woutb, x_bf, bias0, bias1,
                                   h0P, h1P);
  k_gemmX<<<dim3(32, 24), 256, 0, stream>>>(x_bf, W0cat, bias0, XP);
  k_recur<<<128, 256, 0, stream>>>(U0cat, U1W, XP, bias1, hidden, h0P, h1P,
                                   r0P, r1P, flags, out + (size_t)TB * V_);
  k_gemmL<<<2560, 256, 0, stream>>>(h1P + BH, Woutb, bout, out);
}

// Round 17
// 1268.519 us; speedup vs baseline: 1.3072x; 1.0894x over previous
//
#include <hip/hip_runtime.h>
#include <hip/hip_bf16.h>

#define T_ 64
#define B_ 64
#define E_ 512
#define H_ 1024
#define V_ 10000
#define TB 4096   // T_*B_
#define BH 65536  // B_*H_

typedef unsigned short u16;
typedef unsigned int u32;
typedef unsigned long long u64;
typedef __attribute__((ext_vector_type(8))) short short8v;
typedef __attribute__((ext_vector_type(4))) float f32x4;

__device__ inline f32x4 mfma_bf16(short8v a, short8v b, f32x4 c) {
  return __builtin_amdgcn_mfma_f32_16x16x32_bf16(a, b, c, 0, 0, 0);
}

__device__ inline u16 f2bf(float f) {
  unsigned u = __float_as_uint(f);
  unsigned r = (u + 0x7fffu + ((u >> 16) & 1u)) >> 16;
  return (u16)r;
}
__device__ inline float bf2f(u16 h) { return __uint_as_float(((unsigned)h) << 16); }

// ---------------- merged prep ----------------

__global__ void k_prep(const float* __restrict__ Wr0, const float* __restrict__ Wz0,
                       const float* __restrict__ Wh0, const float* __restrict__ Ur,
                       const float* __restrict__ Uz, const float* __restrict__ Uh,
                       const float* __restrict__ WrR, const float* __restrict__ WzR,
                       const float* __restrict__ WhR, const float* __restrict__ Wout,
                       const int* __restrict__ idx, const float* __restrict__ emb,
                       const float* __restrict__ bur, const float* __restrict__ buz,
                       const float* __restrict__ buh, const float* __restrict__ brR,
                       const float* __restrict__ bzR, const float* __restrict__ bhR,
                       const float* __restrict__ hidden,
                       u16* __restrict__ W0cat, u16* __restrict__ U0cat,
                       u16* __restrict__ U1W, u16* __restrict__ Woutb,
                       u16* __restrict__ x_bf, float* __restrict__ bias0,
                       float* __restrict__ bias1, u16* __restrict__ h0P,
                       u16* __restrict__ h1P) {
  const int HE = H_ * E_;
  const int HH = H_ * H_;
  const size_t n0 = 3u * (size_t)HE;
  const size_t n1 = n0 + 3u * (size_t)HH;
  const size_t n2 = n1 + 3072u * 2048u;
  const size_t n3 = n2 + (size_t)V_ * H_;
  const size_t n4 = n3 + (size_t)TB * E_;
  const size_t n5 = n4 + 3072;
  const size_t n6 = n5 + 65536;
  size_t i = (size_t)blockIdx.x * 256 + threadIdx.x;
  const size_t stride = (size_t)gridDim.x * 256;
  for (; i < n6; i += stride) {
    if (i < n0) {
      int g = (int)(i >> 19), off = (int)(i & (HE - 1));
      const float* s = g == 0 ? Wr0 : (g == 1 ? Wz0 : Wh0);
      W0cat[i] = f2bf(s[off]);
    } else if (i < n1) {
      size_t j = i - n0;
      int g = (int)(j >> 20), off = (int)(j & (HH - 1));
      const float* s = g == 0 ? Ur : (g == 1 ? Uz : Uh);
      U0cat[j] = f2bf(s[off]);
    } else if (i < n2) {
      size_t k = i - n1;
      int row = (int)(k >> 11), kk = (int)(k & 2047);
      int g = row >> 10, jj = row & 1023;
      const float* su = g == 0 ? Ur : (g == 1 ? Uz : Uh);
      const float* sw = g == 0 ? WrR : (g == 1 ? WzR : WhR);
      float v = (kk < 1024) ? su[(size_t)HH + (size_t)jj * 1024 + kk]
                            : sw[(size_t)jj * 1024 + (kk - 1024)];
      U1W[k] = f2bf(v);
    } else if (i < n3) {
      size_t m = i - n2;
      Woutb[m] = f2bf(Wout[m]);
    } else if (i < n4) {
      size_t j = i - n3;
      int row = (int)(j >> 9), e = (int)(j & 511);
      x_bf[j] = f2bf(emb[(size_t)idx[row] * E_ + e]);
    } else if (i < n5) {
      int j = (int)(i - n4);
      int seg = j >> 10, col = j & 1023;
      float b0, b1;
      if (seg == 0)      { b0 = bur[col]; b1 = brR[col] + bur[H_ + col]; }
      else if (seg == 1) { b0 = buz[col]; b1 = bzR[col] + buz[H_ + col]; }
      else               { b0 = buh[col]; b1 = bhR[col] + buh[H_ + col]; }
      bias0[j] = b0; bias1[j] = b1;
    } else {
      int j = (int)(i - n5);
      int row = j >> 10, c = j & 1023;
      int dst = ((c >> 4) << 10) + (row << 4) + (c & 15);
      h0P[dst] = f2bf(hidden[j]);
      h1P[dst] = f2bf(hidden[BH + j]);
    }
  }
}

// ---------------- GEMM 1: X = x_emb @ W0cat^T + bias0, packed-X bf16 out ----------------

__global__ __launch_bounds__(256, 2) void k_gemmX(const u16* __restrict__ A,
                                                  const u16* __restrict__ Wt,
                                                  const float* __restrict__ bias,
                                                  u16* __restrict__ XP) {
  const int m0 = blockIdx.x * 128, n0 = blockIdx.y * 128;
  const int wid = threadIdx.x >> 6, lane = threadIdx.x & 63;
  const int wm = wid >> 1, wn = wid & 1;
  const int lrow = lane & 15, lk = (lane >> 4) * 8;
  f32x4 acc[4][4] = {};
  const u16* Ab = A + (size_t)(m0 + wm * 64 + lrow) * 512 + lk;
  const u16* Wb = Wt + (size_t)(n0 + wn * 64 + lrow) * 512 + lk;
  for (int ks = 0; ks < 512; ks += 32) {
    short8v a[4], b[4];
#pragma unroll
    for (int f = 0; f < 4; f++) a[f] = *(const short8v*)(Ab + (size_t)f * 16 * 512 + ks);
#pragma unroll
    for (int f = 0; f < 4; f++) b[f] = *(const short8v*)(Wb + (size_t)f * 16 * 512 + ks);
#pragma unroll
    for (int i = 0; i < 4; i++)
#pragma unroll
      for (int j = 0; j < 4; j++) acc[i][j] = mfma_bf16(a[i], b[j], acc[i][j]);
  }
  const int drow0 = (lane >> 4) * 4, dcol = lane & 15;
#pragma unroll
  for (int i = 0; i < 4; i++)
#pragma unroll
    for (int j = 0; j < 4; j++) {
      int col = n0 + wn * 64 + j * 16 + dcol;
      float bv = bias[col];
      int g = col >> 10, cg = (col & 1023) >> 4, cc = col & 15;
#pragma unroll
      for (int v = 0; v < 4; v++) {
        int row = m0 + wm * 64 + i * 16 + drow0 + v;
        int t = row >> 6, rr = row & 63;
        XP[(((size_t)t * 64 + cg) * 64 + rr) * 48 + g * 16 + cc] = f2bf(acc[i][j][v] + bv);
      }
    }
}

// ---------------- fused recurrence + streaming logits workers ----------------
// grid 2656 x 256 thr. gbid<64: L0; 64..127: L1 (persistent, co-resident).
// gbid>=128: logits workers, w = gbid-128; mt = w/79 (timestep pair, ascending so
// dispatch order matches readiness), nt = w%79. Worker polls f1s for h1[2mt+2]
// published (slots >= 4mt+4), computes 128x128 logits tile, exits.
// Producers: R15 structure (burst loads, R-first publish, parallel waits).

template <int SLP>
__device__ inline void pollall(const int* slots, int tgt) {
  const int lane = threadIdx.x & 63;
  const int* p = slots + lane * 32;
  for (;;) {
    int v = __hip_atomic_load(p, __ATOMIC_RELAXED, __HIP_MEMORY_SCOPE_AGENT);
    if (__all(v >= tgt)) break;
    __builtin_amdgcn_s_sleep(SLP);
  }
}

__global__ __launch_bounds__(256, 1) void k_recur(
    const u16* __restrict__ U0, const u16* __restrict__ U1W,
    const u16* __restrict__ XP, const float* __restrict__ bias1,
    const float* __restrict__ hidden,
    u16* __restrict__ h0P, u16* __restrict__ h1P,
    u16* __restrict__ r0P, u16* __restrict__ r1P,
    const u16* __restrict__ Woutb, const float* __restrict__ bout,
    float* __restrict__ out,
    int* __restrict__ flags, float* __restrict__ hfin) {
  __shared__ __align__(16) u16 wlds[65536];  // 128 KiB

  const int tid = threadIdx.x, gbid = blockIdx.x;
  const int wid = tid >> 6, lane = tid & 63;
  const int lrow = lane & 15, lk = (lane >> 4) * 8;
  const int drow0 = (lane >> 4) * 4, dcol = lane & 15;
  int* f0s = flags;
  int* f1s = flags + 2048;

  if (gbid >= 128) {
    // ================= logits worker =================
    const int w = gbid - 128;
    const int mt = w / 79, nt = w % 79;
    const int m0 = mt * 128, n0 = nt * 128;
    const int wm = wid >> 1, wn = wid & 1;
    const int lkb = lk >> 4, lkc = lk & 15;
    // wait for h1[2*mt+2] published: all f1s slots >= 4*mt+4
    if (wid == 0) {
      int tgt = 4 * mt + 4;
      pollall<32>(f1s, tgt > 2 * T_ ? 2 * T_ : tgt);
    }
    __syncthreads();
    const u16* AP = h1P + BH;  // slab t+1 for row-block t
    f32x4 acc[4][4] = {};
    const int rowhi = (m0 + wm * 64) >> 6;
    const u16* Ab = AP + (size_t)rowhi * BH + (size_t)lkb * 1024 + lrow * 16 + lkc;
    const u16* Wb = Woutb + (size_t)(n0 + wn * 64 + lrow) * 1024 + lk;
    bool nvalid[4];
#pragma unroll
    for (int f = 0; f < 4; f++) nvalid[f] = (n0 + wn * 64 + f * 16 + lrow) < V_;
    const short8v zv = {};
    for (int ks = 0; ks < 1024; ks += 32) {
      short8v a[4], b[4];
#pragma unroll
      for (int f = 0; f < 4; f++) a[f] = *(const short8v*)(Ab + ks * 64 + f * 256);
#pragma unroll
      for (int f = 0; f < 4; f++)
        b[f] = nvalid[f] ? *(const short8v*)(Wb + (size_t)f * 16 * 1024 + ks) : zv;
#pragma unroll
      for (int i = 0; i < 4; i++)
#pragma unroll
        for (int j = 0; j < 4; j++) acc[i][j] = mfma_bf16(a[i], b[j], acc[i][j]);
    }
#pragma unroll
    for (int i = 0; i < 4; i++)
#pragma unroll
      for (int j = 0; j < 4; j++) {
        int col = n0 + wn * 64 + j * 16 + dcol;
        if (col >= V_) continue;
        float bv = bout[col];
#pragma unroll
        for (int v = 0; v < 4; v++) {
          int row = m0 + wm * 64 + i * 16 + drow0 + v;
          out[(size_t)row * V_ + col] = acc[i][j][v] + bv;
        }
      }
    return;
  }

  // ================= producers =================
  const int lay = gbid >> 6;
  const int cg = gbid & 63;
  const int jr = cg * 16;
  const int lk3 = lk >> 3, x7 = lrow & 7;
  const int abase = (lk >> 4) * 1024 + (wid * 16 + lrow) * 16 + (lk & 15);
  const int KLS = lay ? 11 : 10;
  int* myslot = (lay ? f1s : f0s) + cg * 32;

  {  // stage weights into LDS (swizzled 16B chunks)
    const u16* Wg = lay ? U1W : U0;
    const int lCPR = lay ? 8 : 7;
    const int NG = lay ? 2 : 3;
    const int total = NG << (4 + lCPR);
    const int KL = 1 << KLS;
    for (int idx = tid; idx < total; idx += 256) {
      int r16 = idx >> lCPR;
      int ch = idx & ((1 << lCPR) - 1);
      int g = r16 >> 4, r = r16 & 15;
      short8v v = *(const short8v*)(Wg + (size_t)((g << 10) + jr + r) * KL + (ch << 3));
      *(short8v*)&wlds[((size_t)r16 << KLS) + ((ch ^ (r & 7)) << 3)] = v;
    }
  }
  __syncthreads();

  const int lbR = lrow << KLS;
  const int lbZ = (16 + lrow) << KLS;
  const int lbH = (32 + lrow) << KLS;  // L0 only
  const u16* Whg = U1W + (size_t)(2048 + jr + lrow) * 2048 + lk;  // L1 Wh (global)
  const int orow = wid * 16 + drow0;

  float hreg[4];
#pragma unroll
  for (int v = 0; v < 4; v++)
    hreg[v] = hidden[(size_t)lay * BH + (size_t)(orow + v) * 1024 + jr + dcol];

  if (!lay) {
    // ================= layer 0 =================
    float xr[4], xz[4], xh[4];
    {
      const u16* xb = XP + (((size_t)0 * 64 + cg) * 64 + orow) * 48 + dcol;
#pragma unroll
      for (int v = 0; v < 4; v++) {
        xr[v] = bf2f(xb[v * 48]);
        xz[v] = bf2f(xb[v * 48 + 16]);
        xh[v] = bf2f(xb[v * 48 + 32]);
      }
    }
    for (int t = 0; t < T_; t++) {
      float zreg[4];
      if (t) { if (wid == 0) pollall<1>(f0s, 2 * t); __syncthreads(); }
      // burst h0[t]
      short8v av[32];
      {
        const u16* Ab = h0P + (size_t)t * BH + abase;
#pragma unroll
        for (int i = 0; i < 32; i++) av[i] = *(const short8v*)(Ab + i * 2048);
      }
      // R gate only -> publish rh early
      f32x4 ar = {};
#pragma unroll
      for (int i = 0; i < 32; i++) {
        const int sw = (((i * 4) + lk3) ^ x7) << 3;
        ar = mfma_bf16(av[i], *(short8v*)&wlds[lbR + sw], ar);
      }
      u16* rtile = r0P + (size_t)t * BH + (size_t)cg * 1024;
#pragma unroll
      for (int v = 0; v < 4; v++) {
        float r = 1.f / (1.f + __expf(-(ar[v] + xr[v])));
        u16 me = f2bf(r * hreg[v]);
        int oth = __shfl_xor((int)me, 1);
        if (!(dcol & 1)) {
          u32 pk = (u32)me | ((u32)(u16)oth << 16);
          __hip_atomic_store((u32*)(rtile + (orow + v) * 16 + dcol), pk,
                             __ATOMIC_RELAXED, __HIP_MEMORY_SCOPE_AGENT);
        }
      }
      asm volatile("s_waitcnt vmcnt(0)" ::: "memory");
      __syncthreads();
      if (tid == 0)
        __hip_atomic_store(myslot, 2 * t + 1, __ATOMIC_RELAXED, __HIP_MEMORY_SCOPE_AGENT);
      // Z gate (reuses av) — hides signal visibility
      f32x4 az = {};
#pragma unroll
      for (int i = 0; i < 32; i++) {
        const int sw = (((i * 4) + lk3) ^ x7) << 3;
        az = mfma_bf16(av[i], *(short8v*)&wlds[lbZ + sw], az);
      }
#pragma unroll
      for (int v = 0; v < 4; v++) zreg[v] = 1.f / (1.f + __expf(-(az[v] + xz[v])));
      // prefetch X[t+1] — hides rh wait
      float nxr[4], nxz[4], nxh[4];
      {
        int tn = t + 1 < T_ ? t + 1 : T_ - 1;
        const u16* xb = XP + (((size_t)tn * 64 + cg) * 64 + orow) * 48 + dcol;
#pragma unroll
        for (int v = 0; v < 4; v++) {
          nxr[v] = bf2f(xb[v * 48]);
          nxz[v] = bf2f(xb[v * 48 + 16]);
          nxh[v] = bf2f(xb[v * 48 + 32]);
        }
      }
      // wait rh0[t]
      if (wid == 0) pollall<1>(f0s, 2 * t + 1);
      __syncthreads();
      // stage B
      f32x4 ah = {};
      {
        const u16* Abr = r0P + (size_t)t * BH + abase;
        short8v avr[32];
#pragma unroll
        for (int i = 0; i < 32; i++) avr[i] = *(const short8v*)(Abr + i * 2048);
#pragma unroll
        for (int i = 0; i < 32; i++) {
          const int sw = (((i * 4) + lk3) ^ x7) << 3;
          ah = mfma_bf16(avr[i], *(short8v*)&wlds[lbH + sw], ah);
        }
      }
      u16* htile = h0P + (size_t)(t + 1) * BH + (size_t)cg * 1024;
#pragma unroll
      for (int v = 0; v < 4; v++) {
        float th = tanhf(ah[v] + xh[v]);
        float hn = (1.f - zreg[v]) * hreg[v] + zreg[v] * th;
        hreg[v] = hn;
        u16 me = f2bf(hn);
        int oth = __shfl_xor((int)me, 1);
        if (!(dcol & 1)) {
          u32 pk = (u32)me | ((u32)(u16)oth << 16);
          __hip_atomic_store((u32*)(htile + (orow + v) * 16 + dcol), pk,
                             __ATOMIC_RELAXED, __HIP_MEMORY_SCOPE_AGENT);
        }
        if (t == T_ - 1)
          hfin[(size_t)(orow + v) * 1024 + jr + dcol] = hn;
      }
      asm volatile("s_waitcnt vmcnt(0)" ::: "memory");
      __syncthreads();
      if (tid == 0)
        __hip_atomic_store(myslot, 2 * t + 2, __ATOMIC_RELAXED, __HIP_MEMORY_SCOPE_AGENT);
#pragma unroll
      for (int v = 0; v < 4; v++) { xr[v] = nxr[v]; xz[v] = nxz[v]; xh[v] = nxh[v]; }
    }
  } else {
    // ================= layer 1 =================
    float bR = bias1[jr + dcol];
    float bZ = bias1[1024 + jr + dcol];
    float bH = bias1[2048 + jr + dcol];
    if (wid == 0) pollall<1>(f0s, 2);  // h0[1] ready before first A-part1
    __syncthreads();
    for (int t = 0; t < T_; t++) {
      float zreg[4];
      const u16* Ab0 = h0P + (size_t)(t + 1) * BH + abase;
      // ---- A part 1: h0[t+1] burst (av0 kept live for B1) ----
      f32x4 ar = {}, az = {};
      short8v av0[32];
#pragma unroll
      for (int i = 0; i < 32; i++) av0[i] = *(const short8v*)(Ab0 + i * 2048);
#pragma unroll
      for (int i = 0; i < 32; i++) {
        const int sw = ((128 + i * 4 + lk3) ^ x7) << 3;
        ar = mfma_bf16(av0[i], *(short8v*)&wlds[lbR + sw], ar);
        az = mfma_bf16(av0[i], *(short8v*)&wlds[lbZ + sw], az);
      }
      // ---- parallel waits: wave0 -> h1[t]; wave1 -> L0 two steps ahead ----
      if (wid == 0) {
        if (t) pollall<1>(f1s, 2 * t);
      } else if (wid == 1) {
        int tgt = 2 * (t + 2);
        pollall<1>(f0s, tgt > 2 * T_ ? 2 * T_ : tgt);
      }
      __syncthreads();
      // ---- A part 2: burst h1[t]; R first -> publish rh early ----
      short8v av1[32];
      {
        const u16* Ab1 = h1P + (size_t)t * BH + abase;
#pragma unroll
        for (int i = 0; i < 32; i++) av1[i] = *(const short8v*)(Ab1 + i * 2048);
      }
#pragma unroll
      for (int i = 0; i < 32; i++) {
        const int sw = ((i * 4 + lk3) ^ x7) << 3;
        ar = mfma_bf16(av1[i], *(short8v*)&wlds[lbR + sw], ar);
      }
      u16* rtile = r1P + (size_t)t * BH + (size_t)cg * 1024;
#pragma unroll
      for (int v = 0; v < 4; v++) {
        float r = 1.f / (1.f + __expf(-(ar[v] + bR)));
        u16 me = f2bf(r * hreg[v]);
        int oth = __shfl_xor((int)me, 1);
        if (!(dcol & 1)) {
          u32 pk = (u32)me | ((u32)(u16)oth << 16);
          __hip_atomic_store((u32*)(rtile + (orow + v) * 16 + dcol), pk,
                             __ATOMIC_RELAXED, __HIP_MEMORY_SCOPE_AGENT);
        }
      }
      asm volatile("s_waitcnt vmcnt(0)" ::: "memory");
      __syncthreads();
      if (tid == 0)
        __hip_atomic_store(myslot, 2 * t + 1, __ATOMIC_RELAXED, __HIP_MEMORY_SCOPE_AGENT);
      // ---- Z over h1[t] (av1 reuse) — hides signal visibility ----
#pragma unroll
      for (int i = 0; i < 32; i++) {
        const int sw = ((i * 4 + lk3) ^ x7) << 3;
        az = mfma_bf16(av1[i], *(short8v*)&wlds[lbZ + sw], az);
      }
#pragma unroll
      for (int v = 0; v < 4; v++) zreg[v] = 1.f / (1.f + __expf(-(az[v] + bZ)));
      // ---- B part 1: h0[t+1] x Wh (av0 reuse, Whg L2 stream) — hides rh wait ----
      f32x4 ah = {};
#pragma unroll
      for (int i = 0; i < 32; i++)
        ah = mfma_bf16(av0[i], *(const short8v*)(Whg + 1024 + i * 32), ah);
      // ---- wait rh1[t] ----
      if (wid == 0) pollall<1>(f1s, 2 * t + 1);
      __syncthreads();
      // ---- B part 2: burst rh1[t] x Wh ----
      {
        const u16* Abr = r1P + (size_t)t * BH + abase;
        short8v avr[32];
#pragma unroll
        for (int i = 0; i < 32; i++) avr[i] = *(const short8v*)(Abr + i * 2048);
#pragma unroll
        for (int i = 0; i < 32; i++)
          ah = mfma_bf16(avr[i], *(const short8v*)(Whg + i * 32), ah);
      }
      u16* htile = h1P + (size_t)(t + 1) * BH + (size_t)cg * 1024;
#pragma unroll
      for (int v = 0; v < 4; v++) {
        float th = tanhf(ah[v] + bH);
        float hn = (1.f - zreg[v]) * hreg[v] + zreg[v] * th;
        hreg[v] = hn;
        u16 me = f2bf(hn);
        int oth = __shfl_xor((int)me, 1);
        if (!(dcol & 1)) {
          u32 pk = (u32)me | ((u32)(u16)oth << 16);
          __hip_atomic_store((u32*)(htile + (orow + v) * 16 + dcol), pk,
                             __ATOMIC_RELAXED, __HIP_MEMORY_SCOPE_AGENT);
        }
        if (t == T_ - 1)
          hfin[(size_t)BH + (size_t)(orow + v) * 1024 + jr + dcol] = hn;
      }
      asm volatile("s_waitcnt vmcnt(0)" ::: "memory");
      __syncthreads();
      if (tid == 0)
        __hip_atomic_store(myslot, 2 * t + 2, __ATOMIC_RELAXED, __HIP_MEMORY_SCOPE_AGENT);
    }
  }
}

// ---------------- launcher ----------------

extern "C" void kernel_launch(void* const* d_in, const int* in_sizes, int n_in,
                              void* d_out, int out_size, void* d_ws, size_t ws_size,
                              hipStream_t stream) {
  const int* inputs = (const int*)d_in[0];
  const float* hidden = (const float*)d_in[1];
  const float* emb = (const float*)d_in[2];
  const float* Wr0 = (const float*)d_in[3];
  const float* Wz0 = (const float*)d_in[4];
  const float* Wh0 = (const float*)d_in[5];
  const float* WrR = (const float*)d_in[6];
  const float* WzR = (const float*)d_in[7];
  const float* WhR = (const float*)d_in[8];
  const float* brR = (const float*)d_in[9];
  const float* bzR = (const float*)d_in[10];
  const float* bhR = (const float*)d_in[11];
  const float* Ur = (const float*)d_in[12];
  const float* Uz = (const float*)d_in[13];
  const float* Uh = (const float*)d_in[14];
  const float* bur = (const float*)d_in[15];
  const float* buz = (const float*)d_in[16];
  const float* buh = (const float*)d_in[17];
  const float* Wout = (const float*)d_in[18];
  const float* bout = (const float*)d_in[19];
  float* out = (float*)d_out;

  char* ws = (char*)d_ws;
  size_t off = 0;
  auto alloc = [&](size_t bytes) -> void* {
    void* p = ws + off;
    off += (bytes + 255) & ~(size_t)255;
    return p;
  };
  u16* x_bf  = (u16*)alloc((size_t)TB * E_ * 2);
  u16* W0cat = (u16*)alloc((size_t)3072 * 512 * 2);
  u16* U0cat = (u16*)alloc((size_t)3072 * 1024 * 2);
  u16* U1W   = (u16*)alloc((size_t)3072 * 2048 * 2);
  u16* Woutb = (u16*)alloc((size_t)V_ * H_ * 2);
  float* bias0 = (float*)alloc(3072 * 4);
  float* bias1 = (float*)alloc(3072 * 4);
  u16* XP    = (u16*)alloc((size_t)TB * 3072 * 2);
  u16* h0P   = (u16*)alloc((size_t)(T_ + 1) * BH * 2);
  u16* h1P   = (u16*)alloc((size_t)(T_ + 1) * BH * 2);
  u16* r0P   = (u16*)alloc((size_t)T_ * BH * 2);
  u16* r1P   = (u16*)alloc((size_t)T_ * BH * 2);
  int* flags = (int*)alloc(32768);
  (void)ws_size; (void)in_sizes; (void)n_in; (void)out_size;

  (void)hipMemsetAsync(flags, 0, 32768, stream);

  k_prep<<<2048, 256, 0, stream>>>(Wr0, Wz0, Wh0, Ur, Uz, Uh, WrR, WzR, WhR, Wout,
                                   inputs, emb, bur, buz, buh, brR, bzR, bhR, hidden,
                                   W0cat, U0cat, U1W, Woutb, x_bf, bias0, bias1,
                                   h0P, h1P);
  k_gemmX<<<dim3(32, 24), 256, 0, stream>>>(x_bf, W0cat, bias0, XP);
  k_recur<<<128 + 32 * 79, 256, 0, stream>>>(U0cat, U1W, XP, bias1, hidden, h0P, h1P,
                                             r0P, r1P, Woutb, bout, out, flags,
                                             out + (size_t)TB * V_);
}